// Round 5
// baseline (197.179 us; speedup 1.0000x reference)
//
#include <hip/hip_runtime.h>
#include <math.h>

// Problem constants (match reference)
constexpr int C   = 6;
constexpr int NR  = 2048;
constexpr int NC  = 2048;
constexpr int KS  = 10;
constexpr int PAD = 4;              // top/left circular halo

// R8: depth-3 register pipeline (R2 structure, deeper prefetch).
// History: R2 (1-deep prefetch, 12 w/CU) = 67us @ 2.53 TB/s eff, VALU 14%.
// R4 (24 w/CU) = same 2.55 TB/s -> TLP not the lever. R7 (LDS staging) = 48%
// SLOWER (DMA-vs-ds_read bank conflicts 9.3M cyc) -> request count not the
// lever either. Remaining theory: 1-deep load-to-use distance (~170 cyc own
// work) << loaded latency (>=900 cyc HBM + queueing) -> every wave blocks on
// its wait each iter; effective BW pinned ~2.55 TB/s. Fix: 4-slot float4 ring,
// issue row k+3 before consuming row k (distance ~3 iter-slots ~ 3900 cyc).
// Plain HIP loads -> compiler emits counted vmcnt(N) (m97 evidence), no
// barriers anywhere to force a drain. In-flight/CU: 12 waves x 3 rows x 1KB
// = 36KB >> 9.3KB needed for 6.3 TB/s at 900 cyc latency.
constexpr int R     = 32;           // output rows per block
constexpr int NIT   = R + KS - 1;   // 41 streamed H-rows
constexpr int CPT   = 4;            // cols per thread
constexpr int BW    = 256 * CPT;    // 1024 cols per block
constexpr int DEPTH = 4;            // prefetch ring slots (distance 3)
constexpr int DIST  = 3;            // rows ahead

__device__ __constant__ float MTFf[C] = {0.38f, 0.34f, 0.34f, 0.26f, 0.22f, 0.23f};

template<int K> struct IC { static constexpr int v = K; };
template<int K, int N, typename F>
__device__ __forceinline__ void static_for(F&& f) {
    if constexpr (K < N) { f(IC<K>{}); static_for<K + 1, N>(f); }
}

__global__ __launch_bounds__(256, 3)   // 3 blocks/CU (grid 768); VGPR cap 168, ~130 live
void s2_blur_deep(const float* __restrict__ x, float* __restrict__ out)
{
    const int t  = threadIdx.x;
    const int c  = blockIdx.z;
    const int r0 = blockIdx.y * R;
    const int jt = blockIdx.x * BW + t * CPT;   // first output col of this thread

    const float* xc = x   + (size_t)c * NR * NC;
    float*       oc = out + (size_t)c * NR * NC;

    // ---- per-thread fp32 weights (verified absmax 0.0039 << 0.0325) ----
    float w[KS];
    {
        float mtf    = MTFf[c];
        float sig    = 2.0f * sqrtf(-2.0f * logf(mtf) / (float)(M_PI * M_PI));
        float inv2s2 = 1.0f / (2.0f * sig * sig);
        float s = 0.0f;
        #pragma unroll
        for (int d = 0; d < KS; ++d) {
            float cd = -4.5f + (float)d;
            w[d] = expf(-cd * cd * inv2s2);
            s += w[d];
        }
        #pragma unroll
        for (int d = 0; d < KS; ++d) w[d] /= s;
    }

    // ---- per-lane wrapped float4-group offsets (loop-invariant; wrap is a
    // multiple of 4 floats so a 16B group never splits) ----
    const int off0 = (jt - PAD +  0 + NC) & (NC - 1);
    const int off1 = (jt - PAD +  4 + NC) & (NC - 1);
    const int off2 = (jt - PAD +  8 + NC) & (NC - 1);
    const int off3 = (jt - PAD + 12 + NC) & (NC - 1);

    // load strip-row krow into 4 named float4 regs (refs bind to constant ring
    // slots -> SROA keeps everything in VGPRs, no scratch)
    auto load_row = [&](int krow, float4& d0, float4& d1, float4& d2, float4& d3) {
        const float* rp = xc + (size_t)((r0 - PAD + krow + NR) & (NR - 1)) * NC;
        d0 = *(const float4*)(rp + off0);
        d1 = *(const float4*)(rp + off1);
        d2 = *(const float4*)(rp + off2);
        d3 = *(const float4*)(rp + off3);
    };

    // V-pass accumulator ring: slot m%10 holds strip-row m in flight
    float acc[KS][CPT] = {};

    // prefetch ring: slot k%DEPTH holds strip-row k in flight
    float4 buf[DEPTH][4];
    load_row(0, buf[0][0], buf[0][1], buf[0][2], buf[0][3]);
    load_row(1, buf[1][0], buf[1][1], buf[1][2], buf[1][3]);
    load_row(2, buf[2][0], buf[2][1], buf[2][2], buf[2][3]);

    static_for<0, NIT>([&](auto ic) {
        constexpr int k = decltype(ic)::v;

        // issue row k+3 into the slot freed at iter k-1 (distance-3 pipeline)
        if constexpr (k + DIST < NIT) {
            constexpr int sl = (k + DIST) % DEPTH;
            load_row(k + DIST, buf[sl][0], buf[sl][1], buf[sl][2], buf[sl][3]);
        }

        // ---- H-pass for row k (compiler waits only on row k's 4 loads,
        // issued 3 iterations ago; 12 newer loads + stores stay in flight) ----
        constexpr int s0 = k % DEPTH;
        const float f[16] = {buf[s0][0].x, buf[s0][0].y, buf[s0][0].z, buf[s0][0].w,
                             buf[s0][1].x, buf[s0][1].y, buf[s0][1].z, buf[s0][1].w,
                             buf[s0][2].x, buf[s0][2].y, buf[s0][2].z, buf[s0][2].w,
                             buf[s0][3].x, buf[s0][3].y, buf[s0][3].z, buf[s0][3].w};
        float H[CPT];
        #pragma unroll
        for (int q = 0; q < CPT; ++q) {
            float a = 0.0f;
            #pragma unroll
            for (int d = 0; d < KS; ++d) a = fmaf(w[d], f[q + d], a);
            H[q] = a;
        }

        // ---- V-pass ring update: H row k feeds strip rows m = k-o, weight w[o] ----
        #pragma unroll
        for (int o = 0; o < KS; ++o) {
            const int m = k - o;
            if (m >= 0 && m < R) {
                const int s = m % KS;
                #pragma unroll
                for (int q = 0; q < CPT; ++q)
                    acc[s][q] = fmaf(w[o], H[q], acc[s][q]);
            }
        }

        // ---- emit finished strip row m = k-9 ----
        if constexpr (k >= KS - 1) {
            constexpr int m = k - (KS - 1);
            constexpr int sl = m % KS;
            float* orow = oc + (size_t)(r0 + m) * NC;   // wave-uniform base
            *(float4*)(orow + jt) = make_float4(acc[sl][0], acc[sl][1], acc[sl][2], acc[sl][3]);
            #pragma unroll
            for (int q = 0; q < CPT; ++q) acc[sl][q] = 0.0f;
        }
    });
}

extern "C" void kernel_launch(void* const* d_in, const int* in_sizes, int n_in,
                              void* d_out, int out_size, void* d_ws, size_t ws_size,
                              hipStream_t stream) {
    const float* x = (const float*)d_in[0];
    float* out = (float*)d_out;
    dim3 grid(NC / BW, NR / R, C);   // 2 x 64 x 6 = 768 blocks = 3 blocks/CU
    dim3 block(256);
    s2_blur_deep<<<grid, block, 0, stream>>>(x, out);
}